// Round 1
// baseline (197.325 us; speedup 1.0000x reference)
//
#include <hip/hip_runtime.h>
#include <math.h>

// YOLO box decode: (32, 3*85, 52, 52) -> (32*3*52*52, 85)
// Per (b,a) slab: 85x2704 -> 2704x85 transpose + channel-wise transform.
// Memory-bound; LDS-tiled transpose so both read and write are coalesced.

#define NSPAT   2704   // 52*52
#define TILE_S  104    // spatial positions per block (2704 = 26*104, no tail)
#define NTILES  26
#define NCH     85     // 5 + 80 classes
#define PAD_ROW 87     // 85 padded: stride 87 % 32 = 23 (coprime) -> ~2-way LDS aliasing (free)
#define NSLAB   96     // 32 batches * 3 anchors

__global__ __launch_bounds__(256) void yolo_decode_kernel(
    const float* __restrict__ in, float* __restrict__ out) {
  __shared__ float tile[TILE_S * PAD_ROW];

  const int t    = blockIdx.x;   // tile within slab
  const int slab = blockIdx.y;   // b*3 + a
  const int a    = slab % 3;     // anchor index (ANCHOR_MASK = [0,1,2])

  // anchors: w = ANCHORS[2a] in {10,16,33}, h = ANCHORS[2a+1] in {13,30,23}
  const float aw = (a == 0) ? 10.0f : (a == 1) ? 16.0f : 33.0f;
  const float ah = (a == 0) ? 13.0f : (a == 1) ? 30.0f : 23.0f;

  const int base = slab * (NCH * NSPAT);  // same flat base for input and output slabs
  const int s0   = t * TILE_S;

  // ---- Read phase: coalesced reads along spatial dim, transform, stage to LDS ----
  // Lanes sweep idx = c*TILE_S + s; consecutive lanes -> consecutive s -> coalesced.
  for (int idx = threadIdx.x; idx < NCH * TILE_S; idx += 256) {
    const int c = idx / TILE_S;
    const int s = idx - c * TILE_S;
    float v = in[base + c * NSPAT + s0 + s];
    if (c < 5) {
      const int sg = s0 + s;           // global spatial index: h*52 + w
      if (c == 0) {
        v = 1.0f / (1.0f + __expf(-v)) + (float)(sg % 52);       // bx = sigmoid + grid_x
      } else if (c == 1) {
        v = 1.0f / (1.0f + __expf(-v)) + (float)(sg / 52);       // by = sigmoid + grid_y
      } else if (c == 2) {
        v = __expf(v * (1.0f / 416.0f)) * aw;                    // bw
      } else if (c == 3) {
        v = __expf(v * (1.0f / 416.0f)) * ah;                    // bh
      } else {
        v = 1.0f / (1.0f + __expf(-v));                          // conf
      }
    }
    tile[s * PAD_ROW + c] = v;  // stride-87 across lanes: coprime with 32 banks
  }

  __syncthreads();

  // ---- Write phase: block's output is one contiguous run of 104*85 floats ----
  const int obase = base + s0 * NCH;
  for (int idx = threadIdx.x; idx < NCH * TILE_S; idx += 256) {
    const int s = idx / NCH;
    const int c = idx - s * NCH;
    out[obase + idx] = tile[s * PAD_ROW + c];  // LDS stride-1 across lanes: conflict-free
  }
}

extern "C" void kernel_launch(void* const* d_in, const int* in_sizes, int n_in,
                              void* d_out, int out_size, void* d_ws, size_t ws_size,
                              hipStream_t stream) {
  const float* in = (const float*)d_in[0];
  float* out = (float*)d_out;
  dim3 grid(NTILES, NSLAB);
  yolo_decode_kernel<<<grid, 256, 0, stream>>>(in, out);
}

// Round 2
// 157.752 us; speedup vs baseline: 1.2509x; 1.2509x over previous
//
#include <hip/hip_runtime.h>
#include <math.h>

// YOLO box decode: (32, 3*85, 52, 52) -> (32*3*52*52, 85)
// Per (b,a) slab: 85x2704 -> 2704x85 transpose + channel-wise transform.
// Memory-bound; LDS-tiled transpose, float4 on both global phases.
// Block = 512 threads, LDS = 104*85*4 = 35360 B -> 4 blocks/CU -> 32 waves/CU (100%).

#define NSPAT   2704   // 52*52
#define TILE_S  104    // spatial positions per block (2704 = 26*104, no tail)
#define TILE_Q  26     // TILE_S / 4 (float4 groups along s)
#define NTILES  26
#define NCH     85     // 5 + 80 classes
#define NSLAB   96     // 32 batches * 3 anchors

__global__ __launch_bounds__(512) void yolo_decode_kernel(
    const float* __restrict__ in, float* __restrict__ out) {
  __shared__ __align__(16) float tile[TILE_S * NCH];  // output-layout: [s][c], unpadded

  const int t    = blockIdx.x;   // tile within slab
  const int slab = blockIdx.y;   // b*3 + a
  const int a    = slab % 3;     // anchor index (ANCHOR_MASK = [0,1,2])

  // anchors: w = ANCHORS[2a] in {10,16,33}, h = ANCHORS[2a+1] in {13,30,23}
  const float aw = (a == 0) ? 10.0f : (a == 1) ? 16.0f : 33.0f;
  const float ah = (a == 0) ? 13.0f : (a == 1) ? 30.0f : 23.0f;

  const int base = slab * (NCH * NSPAT);  // same flat base for input and output slabs
  const int s0   = t * TILE_S;

  // ---- Read phase: float4 along spatial dim, transform, stage to LDS ----
  // idx = c*TILE_Q + q; lane loads in[base + c*NSPAT + s0 + 4q .. +3] (16B aligned).
  for (int idx = threadIdx.x; idx < NCH * TILE_Q; idx += 512) {
    const int c = idx / TILE_Q;
    const int q = idx - c * TILE_Q;
    const int s = 4 * q;
    float4 v = *(const float4*)(in + base + c * NSPAT + s0 + s);
    float e[4] = {v.x, v.y, v.z, v.w};
    if (c < 5) {
      #pragma unroll
      for (int j = 0; j < 4; ++j) {
        const int sg = s0 + s + j;  // global spatial index: h*52 + w
        float x = e[j];
        if (c == 0)      x = 1.0f / (1.0f + __expf(-x)) + (float)(sg % 52);  // bx
        else if (c == 1) x = 1.0f / (1.0f + __expf(-x)) + (float)(sg / 52);  // by
        else if (c == 2) x = __expf(x * (1.0f / 416.0f)) * aw;               // bw
        else if (c == 3) x = __expf(x * (1.0f / 416.0f)) * ah;               // bh
        else             x = 1.0f / (1.0f + __expf(-x));                     // conf
        e[j] = x;
      }
    }
    #pragma unroll
    for (int j = 0; j < 4; ++j)
      tile[(s + j) * NCH + c] = e[j];  // bank stride 340 (gcd 4 w/ 32) -> ~3-way, free-ish
  }

  __syncthreads();

  // ---- Write phase: block's output is one contiguous run of 104*85 = 8840 floats ----
  // tile is already in flat output order: ds_read_b128 + global_store_dwordx4.
  const float4* tsrc = (const float4*)tile;
  float4* dst = (float4*)(out + base + s0 * NCH);  // 8840*t elements: 16B aligned
  for (int idx = threadIdx.x; idx < (TILE_S * NCH) / 4; idx += 512) {
    dst[idx] = tsrc[idx];
  }
}

extern "C" void kernel_launch(void* const* d_in, const int* in_sizes, int n_in,
                              void* d_out, int out_size, void* d_ws, size_t ws_size,
                              hipStream_t stream) {
  const float* in = (const float*)d_in[0];
  float* out = (float*)d_out;
  dim3 grid(NTILES, NSLAB);
  yolo_decode_kernel<<<grid, 512, 0, stream>>>(in, out);
}

// Round 5
// 156.783 us; speedup vs baseline: 1.2586x; 1.0062x over previous
//
#include <hip/hip_runtime.h>
#include <math.h>

// YOLO box decode: (32, 3*85, 52, 52) -> (32*3*52*52, 85)
// Per-WAVE LDS transpose: each wave owns a 16-spatial x 85-channel tile in a
// private LDS slice. No block-wide barrier -- a wave only reads LDS it wrote
// itself. RACE FIX (R3 post-mortem): explicit s_waitcnt lgkmcnt(0) + compiler
// memory clobber between the LDS scatter-writes and the b128 read-back;
// without it the intra-wave RAW through LDS failed intermittently under
// graph replay. Non-temporal global loads/stores: both streams are touch-once.
// R4 fix: nontemporal builtins need a native clang vector type, not
// HIP_vector_type -> use ext_vector_type(4) float for the NT accesses.

typedef float nat_float4 __attribute__((ext_vector_type(4)));

#define NSPAT   2704          // 52*52
#define NCH     85            // 5 + 80 classes
#define WTILE_S 16            // spatial positions per wave
#define WITEMS  340           // float4 items per wave = 16*85/4
#define NSLOTS  6             // ceil(340/64)
#define WPB     4             // waves per block (256 threads)
#define TILES_PER_SLAB 169    // 2704/16
#define NSLAB   96            // 32 batches * 3 anchors
// grid = 96*169/4 = 4056 blocks; LDS/block = 4*16*85*4 = 21760 B -> 7 blocks/CU
// -> 28 waves/CU (87.5% occupancy)

__global__ __launch_bounds__(256) void yolo_decode_kernel(
    const float* __restrict__ in, float* __restrict__ out) {
  __shared__ __align__(16) float tile[WPB][WTILE_S * NCH];

  const int lane = threadIdx.x & 63;
  const int widx = threadIdx.x >> 6;
  const int gw   = blockIdx.x * WPB + widx;        // global wave id, 0..16223
  const int slab = gw / TILES_PER_SLAB;            // b*3 + a
  const int tt   = gw - slab * TILES_PER_SLAB;     // tile within slab
  const int a    = slab % 3;                       // ANCHOR_MASK = [0,1,2]

  const float aw = (a == 0) ? 10.0f : (a == 1) ? 16.0f : 33.0f;
  const float ah = (a == 0) ? 13.0f : (a == 1) ? 30.0f : 23.0f;

  const int base = slab * (NCH * NSPAT);           // flat slab base (in and out)
  const int s0   = tt * WTILE_S;

  float* slice = tile[widx];

  // ---- Phase 1: issue ALL loads into register slots (6 outstanding VMEM) ----
  // item idx = 4*c + q: channel c (0..84), q-th float4 group (0..3) along s.
  nat_float4 v[NSLOTS];
  #pragma unroll
  for (int k = 0; k < NSLOTS; ++k) {
    const int idx = lane + 64 * k;
    if (idx < WITEMS) {
      const int c = idx >> 2;
      const int q = idx & 3;
      v[k] = __builtin_nontemporal_load(
          (const nat_float4*)(in + base + c * NSPAT + s0 + 4 * q));
    }
  }

  // ---- Phase 2: transform + stage to private LDS slice (output layout) ----
  #pragma unroll
  for (int k = 0; k < NSLOTS; ++k) {
    const int idx = lane + 64 * k;
    if (idx < WITEMS) {
      const int c = idx >> 2;
      const int q = idx & 3;
      float e[4] = {v[k].x, v[k].y, v[k].z, v[k].w};
      if (c < 5) {                 // only idx<20: 20 lanes of slot 0 diverge
        #pragma unroll
        for (int j = 0; j < 4; ++j) {
          const int sg = s0 + 4 * q + j;   // global spatial index: h*52 + w
          float x = e[j];
          if (c == 0)      x = 1.0f / (1.0f + __expf(-x)) + (float)(sg % 52);
          else if (c == 1) x = 1.0f / (1.0f + __expf(-x)) + (float)(sg / 52);
          else if (c == 2) x = __expf(x * (1.0f / 416.0f)) * aw;
          else if (c == 3) x = __expf(x * (1.0f / 416.0f)) * ah;
          else             x = 1.0f / (1.0f + __expf(-x));
          e[j] = x;
        }
      }
      #pragma unroll
      for (int j = 0; j < 4; ++j)
        slice[(4 * q + j) * NCH + c] = e[j];   // ~2-3-way bank aliasing: free
    }
  }

  // RACE FIX: force all this wave's ds_writes to COMPLETE before any ds_read
  // of the read-back phase issues, and forbid compiler reordering across it.
  asm volatile("s_waitcnt lgkmcnt(0)" ::: "memory");

  // ---- Phase 3: contiguous float4 write-out of this wave's 1360 floats ----
  const nat_float4* s4 = (const nat_float4*)slice;
  nat_float4* dst = (nat_float4*)(out + base + s0 * NCH);  // 16B-aligned
  #pragma unroll
  for (int k = 0; k < NSLOTS; ++k) {
    const int idx = lane + 64 * k;
    if (idx < WITEMS) __builtin_nontemporal_store(s4[idx], dst + idx);
  }
}

extern "C" void kernel_launch(void* const* d_in, const int* in_sizes, int n_in,
                              void* d_out, int out_size, void* d_ws, size_t ws_size,
                              hipStream_t stream) {
  const float* in = (const float*)d_in[0];
  float* out = (float*)d_out;
  const int nblocks = (NSLAB * TILES_PER_SLAB) / WPB;  // 4056
  yolo_decode_kernel<<<nblocks, 256, 0, stream>>>(in, out);
}